// Round 14
// baseline (545.660 us; speedup 1.0000x reference)
//
#include <hip/hip_runtime.h>

static inline int idiv_up(int a, int b) { return (a + b - 1) / b; }

typedef __attribute__((ext_vector_type(8))) short bf16x8;
typedef __attribute__((ext_vector_type(4))) float f32x4;

#define NBSHIFT 9           // 512 nodes per bucket
#define BCAP    11264       // edge capacity per bucket (mean ~8192 + 34 sigma)
#define EPB     4096        // edges per binning block (16 per thread)

__device__ __forceinline__ float bf16u_to_f32(unsigned short u) {
    return __uint_as_float(((unsigned int)u) << 16);
}

__device__ __forceinline__ unsigned short f32_to_bf16u(float x) {
    unsigned int b = __float_as_uint(x);
    b += 0x7FFFu + ((b >> 16) & 1u);   // round-to-nearest-even
    return (unsigned short)(b >> 16);
}

// ---------------- init bucket cursors to fixed bases ----------------
__global__ void k_binit(int* __restrict__ bucketCur) {
    if (threadIdx.x < 256) bucketCur[threadIdx.x] = threadIdx.x * BCAP;
}

// ---------------- pass A: bin edges by dst-bucket, packed (localdst<<17 | src) ----------------
__global__ __launch_bounds__(256) void k_bucketA(const int* __restrict__ src,
                                                 const int* __restrict__ dst, int E,
                                                 int* __restrict__ bucketCur,
                                                 int* __restrict__ tmp) {
    __shared__ int bh[256];
    __shared__ int bbase[256];
    const int tid = threadIdx.x;
    const int c0 = blockIdx.x * EPB;
    const int cend = min(c0 + EPB, E);
    bh[tid] = 0;
    __syncthreads();

    int sv[16], dv[16];
#pragma unroll
    for (int i = 0; i < 4; ++i) {
        const int p = c0 + i * 1024 + tid * 4;
        int4 s4 = make_int4(0, 0, 0, 0);
        int4 d4 = make_int4(-1, -1, -1, -1);
        if (p + 4 <= cend) {
            s4 = *(const int4*)(src + p);
            d4 = *(const int4*)(dst + p);
        } else if (p < cend) {
            s4.x = src[p]; d4.x = dst[p];
            if (p + 1 < cend) { s4.y = src[p + 1]; d4.y = dst[p + 1]; }
            if (p + 2 < cend) { s4.z = src[p + 2]; d4.z = dst[p + 2]; }
        }
        sv[i * 4 + 0] = s4.x; sv[i * 4 + 1] = s4.y; sv[i * 4 + 2] = s4.z; sv[i * 4 + 3] = s4.w;
        dv[i * 4 + 0] = d4.x; dv[i * 4 + 1] = d4.y; dv[i * 4 + 2] = d4.z; dv[i * 4 + 3] = d4.w;
    }
#pragma unroll
    for (int i = 0; i < 16; ++i)
        if (dv[i] >= 0) atomicAdd(&bh[dv[i] >> NBSHIFT], 1);
    __syncthreads();
    {
        const int c = bh[tid];
        bbase[tid] = c ? atomicAdd(&bucketCur[tid], c) : 0;  // one global atomic per (block,bucket)
        bh[tid] = 0;                                          // reuse as local cursor
    }
    __syncthreads();
#pragma unroll
    for (int i = 0; i < 16; ++i) {
        if (dv[i] >= 0) {
            const int b = dv[i] >> NBSHIFT;
            const int loc = atomicAdd(&bh[b], 1);             // LDS atomic
            tmp[bbase[b] + loc] = ((dv[i] & ((1 << NBSHIFT) - 1)) << 17) | sv[i];
        }
    }
}

// ---------------- per-bucket: LDS hist -> wave scan -> rowcnt/dinv -> CSR fill ----------------
__global__ __launch_bounds__(512) void k_build(const int* __restrict__ tmp,
                                               const int* __restrict__ bucketCur,
                                               int2* __restrict__ rowcnt,
                                               float* __restrict__ dinv,
                                               int* __restrict__ csr, int N) {
    __shared__ int h[512];
    __shared__ int woff[9];
    const int b = blockIdx.x;
    const int tid = threadIdx.x;
    const int beg = b * BCAP;
    const int ecnt = bucketCur[b] - beg;
    const int node0 = b << NBSHIFT;

    h[tid] = 0;
    __syncthreads();
    for (int i = tid; i < ecnt; i += 512)
        atomicAdd(&h[tmp[beg + i] >> 17], 1);                 // LDS atomic
    __syncthreads();

    const int v = h[tid];
    const int lane = tid & 63;
    const int w = tid >> 6;
    int incl = v;
#pragma unroll
    for (int off = 1; off < 64; off <<= 1) {
        const int y = __shfl_up(incl, off, 64);
        if (lane >= off) incl += y;
    }
    if (lane == 63) woff[w + 1] = incl;
    if (tid == 0) woff[0] = 0;
    __syncthreads();
    if (tid == 0) {
#pragma unroll
        for (int i = 1; i < 8; ++i) woff[i + 1] += woff[i];
    }
    __syncthreads();
    const int rowbase = beg + woff[w] + incl - v;             // exclusive prefix within bucket
    const int node = node0 + tid;
    if (node < N) {
        rowcnt[node] = make_int2(rowbase, v);
        dinv[node]   = rsqrtf((float)v + 1.0f);               // +1 = self loop
    }
    __syncthreads();
    h[tid] = rowbase;                                         // reuse as absolute write cursor
    __syncthreads();
    for (int i = tid; i < ecnt; i += 512) {
        const int p = tmp[beg + i];
        const int pos = atomicAdd(&h[p >> 17], 1);            // LDS atomic
        csr[pos] = p & 0x1FFFF;
    }
}

// ---------------- bf16 MFMA GEMM: t[r] = (A[r]@W) * dinv[r], bf16 out; A fp32 or bf16 ----------------
template<bool ABF16>
__global__ __launch_bounds__(256) void k_gemm(const void* __restrict__ Av,
                                              const float* __restrict__ W,
                                              const float* __restrict__ dinv,
                                              unsigned short* __restrict__ C, int N) {
    __shared__ unsigned short Wt[128 * 128];   // 32 KB
    const int tid = threadIdx.x;

    {   // stage Wt[col][k] = bf16(W[k][col]), swizzle: kus ^ ((col&7)<<3)
        const int col = tid >> 1;
        const int k0  = (tid & 1) * 64;
#pragma unroll
        for (int i = 0; i < 8; ++i) {
            bf16x8 pk;
#pragma unroll
            for (int j = 0; j < 8; ++j)
                pk[j] = (short)f32_to_bf16u(W[(size_t)(k0 + i * 8 + j) * 128 + col]);
            const int kus = k0 + i * 8;
            *(bf16x8*)&Wt[col * 128 + (kus ^ ((col & 7) << 3))] = pk;
        }
    }
    __syncthreads();

    const int wave = tid >> 6;
    const int lane = tid & 63;
    const int lrow = lane & 15;
    const int lgrp = lane >> 4;
    const int rbase = blockIdx.x * 128 + wave * 32;

    f32x4 acc[2][8];
#pragma unroll
    for (int r = 0; r < 2; ++r)
#pragma unroll
        for (int c = 0; c < 8; ++c) acc[r][c] = (f32x4){0.f, 0.f, 0.f, 0.f};

#pragma unroll
    for (int kk = 0; kk < 4; ++kk) {
        const int kbase = kk * 32 + lgrp * 8;
        bf16x8 afrag[2];
#pragma unroll
        for (int r = 0; r < 2; ++r) {
            const int row = rbase + r * 16 + lrow;
            bf16x8 a = (bf16x8){0, 0, 0, 0, 0, 0, 0, 0};
            if (row < N) {
                if constexpr (ABF16) {
                    a = *(const bf16x8*)((const unsigned short*)Av + (size_t)row * 128 + kbase);
                } else {
                    const float* p = (const float*)Av + (size_t)row * 128 + kbase;
                    const float4 f0 = *(const float4*)p;
                    const float4 f1 = *(const float4*)(p + 4);
                    a[0] = (short)f32_to_bf16u(f0.x); a[1] = (short)f32_to_bf16u(f0.y);
                    a[2] = (short)f32_to_bf16u(f0.z); a[3] = (short)f32_to_bf16u(f0.w);
                    a[4] = (short)f32_to_bf16u(f1.x); a[5] = (short)f32_to_bf16u(f1.y);
                    a[6] = (short)f32_to_bf16u(f1.z); a[7] = (short)f32_to_bf16u(f1.w);
                }
            }
            afrag[r] = a;
        }
#pragma unroll
        for (int c = 0; c < 8; ++c) {
            const int col = c * 16 + lrow;
            const bf16x8 bb = *(const bf16x8*)&Wt[col * 128 + (kbase ^ ((col & 7) << 3))];
            acc[0][c] = __builtin_amdgcn_mfma_f32_16x16x32_bf16(afrag[0], bb, acc[0][c], 0, 0, 0);
            acc[1][c] = __builtin_amdgcn_mfma_f32_16x16x32_bf16(afrag[1], bb, acc[1][c], 0, 0, 0);
        }
    }

    // epilogue: scale by dinv[row]; C/D layout col = lane&15, row = (lane>>4)*4 + reg
#pragma unroll
    for (int r = 0; r < 2; ++r) {
#pragma unroll
        for (int reg = 0; reg < 4; ++reg) {
            const int orow = rbase + r * 16 + lgrp * 4 + reg;
            if (orow < N) {
                const float dv = dinv[orow];
                unsigned short* crow = C + (size_t)orow * 128 + lrow;
#pragma unroll
                for (int c = 0; c < 8; ++c)
                    crow[c * 16] = f32_to_bf16u(acc[r][c][reg] * dv);
            }
        }
    }
}

// ---------------- XCD-local feature-sliced pull ----------------
// slice = blockIdx.x & 7 (maps to XCD via round-robin dispatch); each slice = 16 features
// = 3.2 MB of t -> L2-resident per XCD. Wave = 8 groups x 8 lanes; group g takes every-8th
// edge; lanes read ushort2 (2 features). shfl_xor 8/16/32 merges groups; lanes 0-7 write.
template<int OUT_BF16_RELU>
__global__ __launch_bounds__(256) void k_pull(const int2* __restrict__ rowcnt,
                                              const int* __restrict__ csr,
                                              const unsigned short* __restrict__ t,
                                              const float* __restrict__ dinv,
                                              const float* __restrict__ bias,
                                              void* __restrict__ outv, int N) {
    const int slice = blockIdx.x & 7;
    const int chunk = blockIdx.x >> 3;
    const int wave  = threadIdx.x >> 6;
    const int lane  = threadIdx.x & 63;
    const int g     = lane >> 3;
    const int l     = lane & 7;
    const int f0    = slice * 16;
    const unsigned short* ts = t + f0 + l * 2;   // per-lane feature base

    const float2 bv = *(const float2*)(bias + f0 + l * 2);

#pragma unroll
    for (int sub = 0; sub < 2; ++sub) {
        const int nid = chunk * 8 + wave * 2 + sub;
        if (nid >= N) continue;
        const int2 rc = rowcnt[nid];
        const int end = rc.x + rc.y;
        const float dd = dinv[nid];
        const ushort2 us = *(const ushort2*)(ts + (size_t)nid * 128);

        float a0 = 0.f, a1 = 0.f;
        int j = rc.x + g;
        for (; j + 8 < end; j += 16) {           // 2 gathers in flight per group
            const int s0 = csr[j];
            const int s1 = csr[j + 8];
            const ushort2 u0 = *(const ushort2*)(ts + (size_t)s0 * 128);
            const ushort2 u1 = *(const ushort2*)(ts + (size_t)s1 * 128);
            a0 += bf16u_to_f32(u0.x) + bf16u_to_f32(u1.x);
            a1 += bf16u_to_f32(u0.y) + bf16u_to_f32(u1.y);
        }
        if (j < end) {
            const ushort2 u = *(const ushort2*)(ts + (size_t)csr[j] * 128);
            a0 += bf16u_to_f32(u.x);
            a1 += bf16u_to_f32(u.y);
        }
        // merge the 8 groups
#pragma unroll
        for (int m = 8; m <= 32; m <<= 1) {
            a0 += __shfl_xor(a0, m, 64);
            a1 += __shfl_xor(a1, m, 64);
        }
        a0 = (a0 + bf16u_to_f32(us.x)) * dd + bv.x;
        a1 = (a1 + bf16u_to_f32(us.y)) * dd + bv.y;
        if (lane < 8) {
            if (OUT_BF16_RELU) {
                a0 = fmaxf(a0, 0.f); a1 = fmaxf(a1, 0.f);
                ushort2 o; o.x = f32_to_bf16u(a0); o.y = f32_to_bf16u(a1);
                *(ushort2*)((unsigned short*)outv + (size_t)nid * 128 + f0 + l * 2) = o;
            } else {
                *(float2*)((float*)outv + (size_t)nid * 128 + f0 + l * 2) = make_float2(a0, a1);
            }
        }
    }
}

extern "C" void kernel_launch(void* const* d_in, const int* in_sizes, int n_in,
                              void* d_out, int out_size, void* d_ws, size_t ws_size,
                              hipStream_t stream) {
    const float* x   = (const float*)d_in[0];
    const int*   ei  = (const int*)d_in[1];
    const float* W1  = (const float*)d_in[2];
    const float* b1  = (const float*)d_in[3];
    const float* W2  = (const float*)d_in[4];
    const float* b2  = (const float*)d_in[5];
    float*       out = (float*)d_out;

    const int N = in_sizes[0] / 128;
    const int E = in_sizes[1] / 2;
    const int* esrc = ei;
    const int* edst = ei + E;
    const size_t NF = (size_t)N * 128;
    const int nbk = idiv_up(N, 1 << NBSHIFT);   // buckets (196 for N=100k)
    const int ebl = idiv_up(E, EPB);            // binning blocks

    // workspace: bucketCur[256], rowcnt[N] int2, dinv[N], t/h bf16[NF], tmp/csr[(nbk+1)*BCAP] ~ 72 MB
    char* ws = (char*)d_ws;
    size_t o = 0;
    int*   bucketCur = (int*)(ws + o);   o += 256 * 4;              o = (o + 255) & ~(size_t)255;
    int2*  rowcnt    = (int2*)(ws + o);  o += (size_t)N * 8;        o = (o + 255) & ~(size_t)255;
    float* dinv      = (float*)(ws + o); o += (size_t)N * 4;        o = (o + 255) & ~(size_t)255;
    unsigned short* t = (unsigned short*)(ws + o); o += NF * 2;     o = (o + 255) & ~(size_t)255;
    unsigned short* h = (unsigned short*)(ws + o); o += NF * 2;     o = (o + 255) & ~(size_t)255;
    int*   tmp       = (int*)(ws + o);   o += (size_t)(nbk + 1) * BCAP * 4; o = (o + 255) & ~(size_t)255;
    int*   csr       = (int*)(ws + o);   o += (size_t)(nbk + 1) * BCAP * 4;

    // ---- CSR build: 3 kernels, no memsets, no global fine-grain atomics ----
    k_binit  <<<1, 256, 0, stream>>>(bucketCur);
    k_bucketA<<<ebl, 256, 0, stream>>>(esrc, edst, E, bucketCur, tmp);
    k_build  <<<nbk, 512, 0, stream>>>(tmp, bucketCur, rowcnt, dinv, csr, N);

    const int gblocks = idiv_up(N, 128);
    const int pblocks = idiv_up(N, 8) * 8;      // 8 nodes/block x 8 slices

    // ---- layer 1 : h = bf16(relu(dinv*(sum+self) + b1)) ----
    k_gemm<false><<<gblocks, 256, 0, stream>>>(x, W1, dinv, t, N);
    k_pull<1>    <<<pblocks, 256, 0, stream>>>(rowcnt, csr, t, dinv, b1, h, N);

    // ---- layer 2 : out = dinv*(sum+self) + b2 (fp32 into d_out) ----
    k_gemm<true> <<<gblocks, 256, 0, stream>>>(h, W2, dinv, t, N);
    k_pull<0>    <<<pblocks, 256, 0, stream>>>(rowcnt, csr, t, dinv, b2, out, N);
}

// Round 15
// 209.887 us; speedup vs baseline: 2.5998x; 2.5998x over previous
//
#include <hip/hip_runtime.h>

static inline int idiv_up(int a, int b) { return (a + b - 1) / b; }

typedef __attribute__((ext_vector_type(8))) short bf16x8;
typedef __attribute__((ext_vector_type(4))) float f32x4;

#define NBSHIFT 9           // 512 nodes per bucket
#define BCAP    11264       // edge capacity per bucket (mean ~8192 + 34 sigma)
#define EPB     4096        // edges per binning block (16 per thread)

__device__ __forceinline__ float bf16u_to_f32(unsigned short u) {
    return __uint_as_float(((unsigned int)u) << 16);
}

__device__ __forceinline__ unsigned short f32_to_bf16u(float x) {
    unsigned int b = __float_as_uint(x);
    b += 0x7FFFu + ((b >> 16) & 1u);   // round-to-nearest-even
    return (unsigned short)(b >> 16);
}

// ---------------- init bucket cursors to fixed bases ----------------
__global__ void k_binit(int* __restrict__ bucketCur) {
    if (threadIdx.x < 256) bucketCur[threadIdx.x] = threadIdx.x * BCAP;
}

// ---------------- pass A: bin edges by dst-bucket, packed (localdst<<17 | src) ----------------
__global__ __launch_bounds__(256) void k_bucketA(const int* __restrict__ src,
                                                 const int* __restrict__ dst, int E,
                                                 int* __restrict__ bucketCur,
                                                 int* __restrict__ tmp) {
    __shared__ int bh[256];
    __shared__ int bbase[256];
    const int tid = threadIdx.x;
    const int c0 = blockIdx.x * EPB;
    const int cend = min(c0 + EPB, E);
    bh[tid] = 0;
    __syncthreads();

    int sv[16], dv[16];
#pragma unroll
    for (int i = 0; i < 4; ++i) {
        const int p = c0 + i * 1024 + tid * 4;
        int4 s4 = make_int4(0, 0, 0, 0);
        int4 d4 = make_int4(-1, -1, -1, -1);
        if (p + 4 <= cend) {
            s4 = *(const int4*)(src + p);
            d4 = *(const int4*)(dst + p);
        } else if (p < cend) {
            s4.x = src[p]; d4.x = dst[p];
            if (p + 1 < cend) { s4.y = src[p + 1]; d4.y = dst[p + 1]; }
            if (p + 2 < cend) { s4.z = src[p + 2]; d4.z = dst[p + 2]; }
        }
        sv[i * 4 + 0] = s4.x; sv[i * 4 + 1] = s4.y; sv[i * 4 + 2] = s4.z; sv[i * 4 + 3] = s4.w;
        dv[i * 4 + 0] = d4.x; dv[i * 4 + 1] = d4.y; dv[i * 4 + 2] = d4.z; dv[i * 4 + 3] = d4.w;
    }
#pragma unroll
    for (int i = 0; i < 16; ++i)
        if (dv[i] >= 0) atomicAdd(&bh[dv[i] >> NBSHIFT], 1);
    __syncthreads();
    {
        const int c = bh[tid];
        bbase[tid] = c ? atomicAdd(&bucketCur[tid], c) : 0;  // one global atomic per (block,bucket)
        bh[tid] = 0;                                          // reuse as local cursor
    }
    __syncthreads();
#pragma unroll
    for (int i = 0; i < 16; ++i) {
        if (dv[i] >= 0) {
            const int b = dv[i] >> NBSHIFT;
            const int loc = atomicAdd(&bh[b], 1);             // LDS atomic
            tmp[bbase[b] + loc] = ((dv[i] & ((1 << NBSHIFT) - 1)) << 17) | sv[i];
        }
    }
}

// ---------------- per-bucket: LDS hist -> wave scan -> rowcnt/dinv -> CSR fill ----------------
__global__ __launch_bounds__(512) void k_build(const int* __restrict__ tmp,
                                               const int* __restrict__ bucketCur,
                                               int2* __restrict__ rowcnt,
                                               float* __restrict__ dinv,
                                               int* __restrict__ csr, int N) {
    __shared__ int h[512];
    __shared__ int woff[9];
    const int b = blockIdx.x;
    const int tid = threadIdx.x;
    const int beg = b * BCAP;
    const int ecnt = bucketCur[b] - beg;
    const int node0 = b << NBSHIFT;

    h[tid] = 0;
    __syncthreads();
    for (int i = tid; i < ecnt; i += 512)
        atomicAdd(&h[tmp[beg + i] >> 17], 1);                 // LDS atomic
    __syncthreads();

    const int v = h[tid];
    const int lane = tid & 63;
    const int w = tid >> 6;
    int incl = v;
#pragma unroll
    for (int off = 1; off < 64; off <<= 1) {
        const int y = __shfl_up(incl, off, 64);
        if (lane >= off) incl += y;
    }
    if (lane == 63) woff[w + 1] = incl;
    if (tid == 0) woff[0] = 0;
    __syncthreads();
    if (tid == 0) {
#pragma unroll
        for (int i = 1; i < 8; ++i) woff[i + 1] += woff[i];
    }
    __syncthreads();
    const int rowbase = beg + woff[w] + incl - v;             // exclusive prefix within bucket
    const int node = node0 + tid;
    if (node < N) {
        rowcnt[node] = make_int2(rowbase, v);
        dinv[node]   = rsqrtf((float)v + 1.0f);               // +1 = self loop
    }
    __syncthreads();
    h[tid] = rowbase;                                         // reuse as absolute write cursor
    __syncthreads();
    for (int i = tid; i < ecnt; i += 512) {
        const int p = tmp[beg + i];
        const int pos = atomicAdd(&h[p >> 17], 1);            // LDS atomic
        csr[pos] = p & 0x1FFFF;
    }
}

// ---------------- bf16 MFMA GEMM: t[r] = (A[r]@W) * dinv[r], bf16 out; A fp32 or bf16 ----------------
template<bool ABF16>
__global__ __launch_bounds__(256) void k_gemm(const void* __restrict__ Av,
                                              const float* __restrict__ W,
                                              const float* __restrict__ dinv,
                                              unsigned short* __restrict__ C, int N) {
    __shared__ unsigned short Wt[128 * 128];   // 32 KB
    const int tid = threadIdx.x;

    {   // stage Wt[col][k] = bf16(W[k][col]), swizzle: kus ^ ((col&7)<<3)
        const int col = tid >> 1;
        const int k0  = (tid & 1) * 64;
#pragma unroll
        for (int i = 0; i < 8; ++i) {
            bf16x8 pk;
#pragma unroll
            for (int j = 0; j < 8; ++j)
                pk[j] = (short)f32_to_bf16u(W[(size_t)(k0 + i * 8 + j) * 128 + col]);
            const int kus = k0 + i * 8;
            *(bf16x8*)&Wt[col * 128 + (kus ^ ((col & 7) << 3))] = pk;
        }
    }
    __syncthreads();

    const int wave = tid >> 6;
    const int lane = tid & 63;
    const int lrow = lane & 15;
    const int lgrp = lane >> 4;
    const int rbase = blockIdx.x * 128 + wave * 32;

    f32x4 acc[2][8];
#pragma unroll
    for (int r = 0; r < 2; ++r)
#pragma unroll
        for (int c = 0; c < 8; ++c) acc[r][c] = (f32x4){0.f, 0.f, 0.f, 0.f};

#pragma unroll
    for (int kk = 0; kk < 4; ++kk) {
        const int kbase = kk * 32 + lgrp * 8;
        bf16x8 afrag[2];
#pragma unroll
        for (int r = 0; r < 2; ++r) {
            const int row = rbase + r * 16 + lrow;
            bf16x8 a = (bf16x8){0, 0, 0, 0, 0, 0, 0, 0};
            if (row < N) {
                if constexpr (ABF16) {
                    a = *(const bf16x8*)((const unsigned short*)Av + (size_t)row * 128 + kbase);
                } else {
                    const float* p = (const float*)Av + (size_t)row * 128 + kbase;
                    const float4 f0 = *(const float4*)p;
                    const float4 f1 = *(const float4*)(p + 4);
                    a[0] = (short)f32_to_bf16u(f0.x); a[1] = (short)f32_to_bf16u(f0.y);
                    a[2] = (short)f32_to_bf16u(f0.z); a[3] = (short)f32_to_bf16u(f0.w);
                    a[4] = (short)f32_to_bf16u(f1.x); a[5] = (short)f32_to_bf16u(f1.y);
                    a[6] = (short)f32_to_bf16u(f1.z); a[7] = (short)f32_to_bf16u(f1.w);
                }
            }
            afrag[r] = a;
        }
#pragma unroll
        for (int c = 0; c < 8; ++c) {
            const int col = c * 16 + lrow;
            const bf16x8 bb = *(const bf16x8*)&Wt[col * 128 + (kbase ^ ((col & 7) << 3))];
            acc[0][c] = __builtin_amdgcn_mfma_f32_16x16x32_bf16(afrag[0], bb, acc[0][c], 0, 0, 0);
            acc[1][c] = __builtin_amdgcn_mfma_f32_16x16x32_bf16(afrag[1], bb, acc[1][c], 0, 0, 0);
        }
    }

    // epilogue: scale by dinv[row]; C/D layout col = lane&15, row = (lane>>4)*4 + reg
#pragma unroll
    for (int r = 0; r < 2; ++r) {
#pragma unroll
        for (int reg = 0; reg < 4; ++reg) {
            const int orow = rbase + r * 16 + lgrp * 4 + reg;
            if (orow < N) {
                const float dv = dinv[orow];
                unsigned short* crow = C + (size_t)orow * 128 + lrow;
#pragma unroll
                for (int c = 0; c < 8; ++c)
                    crow[c * 16] = f32_to_bf16u(acc[r][c][reg] * dv);
            }
        }
    }
}

// ---------------- fused pull: out[d] = dinv[d]*(sum t'[src] + t'[d]) + b ----------------
// one wave per dst node; lane handles features 2*lane, 2*lane+1 (full 256B row per gather —
// line-optimal; r14 showed feature-slicing regresses 3.3x on FETCH).
// 16-deep three-phase batches; per-node prologue loads hoisted above the loop.
template<int OUT_BF16_RELU>
__global__ __launch_bounds__(256) void k_pull(const int2* __restrict__ rowcnt,
                                              const int* __restrict__ csr,
                                              const unsigned short* __restrict__ t,
                                              const float* __restrict__ dinv,
                                              const float* __restrict__ bias,
                                              void* __restrict__ outv, int N) {
    const int nid = blockIdx.x * 4 + (threadIdx.x >> 6);
    if (nid >= N) return;
    const int lane2 = (threadIdx.x & 63) * 2;
    const int2 rc = rowcnt[nid];
    const int beg = rc.x;
    const int end = rc.x + rc.y;

    // hoisted per-node loads (in flight during the edge loop)
    const float dd = dinv[nid];
    const ushort2 us = *(const ushort2*)(t + (size_t)nid * 128 + lane2);
    const float2 bvec = *(const float2*)(bias + lane2);

    float acc0 = 0.f, acc1 = 0.f;
    int j = beg;

    for (; j + 16 <= end; j += 16) {
        int s[16];
#pragma unroll
        for (int q = 0; q < 16; ++q) s[q] = csr[j + q];
        ushort2 u[16];
#pragma unroll
        for (int q = 0; q < 16; ++q)
            u[q] = *(const ushort2*)(t + (size_t)s[q] * 128 + lane2);
#pragma unroll
        for (int q = 0; q < 16; ++q) {
            acc0 += bf16u_to_f32(u[q].x);
            acc1 += bf16u_to_f32(u[q].y);
        }
    }
    if (j + 8 <= end) {
        int s[8];
#pragma unroll
        for (int q = 0; q < 8; ++q) s[q] = csr[j + q];
        ushort2 u[8];
#pragma unroll
        for (int q = 0; q < 8; ++q)
            u[q] = *(const ushort2*)(t + (size_t)s[q] * 128 + lane2);
#pragma unroll
        for (int q = 0; q < 8; ++q) {
            acc0 += bf16u_to_f32(u[q].x);
            acc1 += bf16u_to_f32(u[q].y);
        }
        j += 8;
    }
    if (j + 4 <= end) {
        int s[4];
#pragma unroll
        for (int q = 0; q < 4; ++q) s[q] = csr[j + q];
        ushort2 u[4];
#pragma unroll
        for (int q = 0; q < 4; ++q)
            u[q] = *(const ushort2*)(t + (size_t)s[q] * 128 + lane2);
#pragma unroll
        for (int q = 0; q < 4; ++q) {
            acc0 += bf16u_to_f32(u[q].x);
            acc1 += bf16u_to_f32(u[q].y);
        }
        j += 4;
    }
    for (; j + 2 <= end; j += 2) {
        const int s0 = csr[j];
        const int s1 = csr[j + 1];
        const ushort2 u0 = *(const ushort2*)(t + (size_t)s0 * 128 + lane2);
        const ushort2 u1 = *(const ushort2*)(t + (size_t)s1 * 128 + lane2);
        acc0 += bf16u_to_f32(u0.x); acc1 += bf16u_to_f32(u0.y);
        acc0 += bf16u_to_f32(u1.x); acc1 += bf16u_to_f32(u1.y);
    }
    if (j < end) {
        const ushort2 u = *(const ushort2*)(t + (size_t)csr[j] * 128 + lane2);
        acc0 += bf16u_to_f32(u.x); acc1 += bf16u_to_f32(u.y);
    }

    // self loop + final dinv[d] scale + bias
    acc0 = (acc0 + bf16u_to_f32(us.x)) * dd + bvec.x;
    acc1 = (acc1 + bf16u_to_f32(us.y)) * dd + bvec.y;
    if (OUT_BF16_RELU) {
        acc0 = fmaxf(acc0, 0.f); acc1 = fmaxf(acc1, 0.f);
        ushort2 o; o.x = f32_to_bf16u(acc0); o.y = f32_to_bf16u(acc1);
        *(ushort2*)((unsigned short*)outv + (size_t)nid * 128 + lane2) = o;
    } else {
        *(float2*)((float*)outv + (size_t)nid * 128 + lane2) = make_float2(acc0, acc1);
    }
}

extern "C" void kernel_launch(void* const* d_in, const int* in_sizes, int n_in,
                              void* d_out, int out_size, void* d_ws, size_t ws_size,
                              hipStream_t stream) {
    const float* x   = (const float*)d_in[0];
    const int*   ei  = (const int*)d_in[1];
    const float* W1  = (const float*)d_in[2];
    const float* b1  = (const float*)d_in[3];
    const float* W2  = (const float*)d_in[4];
    const float* b2  = (const float*)d_in[5];
    float*       out = (float*)d_out;

    const int N = in_sizes[0] / 128;
    const int E = in_sizes[1] / 2;
    const int* esrc = ei;
    const int* edst = ei + E;
    const size_t NF = (size_t)N * 128;
    const int nbk = idiv_up(N, 1 << NBSHIFT);   // buckets (196 for N=100k)
    const int ebl = idiv_up(E, EPB);            // binning blocks

    // workspace: bucketCur[256], rowcnt[N] int2, dinv[N], t/h bf16[NF], tmp/csr[(nbk+1)*BCAP] ~ 72 MB
    char* ws = (char*)d_ws;
    size_t o = 0;
    int*   bucketCur = (int*)(ws + o);   o += 256 * 4;              o = (o + 255) & ~(size_t)255;
    int2*  rowcnt    = (int2*)(ws + o);  o += (size_t)N * 8;        o = (o + 255) & ~(size_t)255;
    float* dinv      = (float*)(ws + o); o += (size_t)N * 4;        o = (o + 255) & ~(size_t)255;
    unsigned short* t = (unsigned short*)(ws + o); o += NF * 2;     o = (o + 255) & ~(size_t)255;
    unsigned short* h = (unsigned short*)(ws + o); o += NF * 2;     o = (o + 255) & ~(size_t)255;
    int*   tmp       = (int*)(ws + o);   o += (size_t)(nbk + 1) * BCAP * 4; o = (o + 255) & ~(size_t)255;
    int*   csr       = (int*)(ws + o);   o += (size_t)(nbk + 1) * BCAP * 4;

    // ---- CSR build: 3 kernels, no memsets, no global fine-grain atomics ----
    k_binit  <<<1, 256, 0, stream>>>(bucketCur);
    k_bucketA<<<ebl, 256, 0, stream>>>(esrc, edst, E, bucketCur, tmp);
    k_build  <<<nbk, 512, 0, stream>>>(tmp, bucketCur, rowcnt, dinv, csr, N);

    const int gblocks = idiv_up(N, 128);
    const int pblocks = idiv_up(N, 4);

    // ---- layer 1 : h = bf16(relu(dinv*(sum+self) + b1)) ----
    k_gemm<false><<<gblocks, 256, 0, stream>>>(x, W1, dinv, t, N);
    k_pull<1>    <<<pblocks, 256, 0, stream>>>(rowcnt, csr, t, dinv, b1, h, N);

    // ---- layer 2 : out = dinv*(sum+self) + b2 (fp32 into d_out) ----
    k_gemm<true> <<<gblocks, 256, 0, stream>>>(h, W2, dinv, t, N);
    k_pull<0>    <<<pblocks, 256, 0, stream>>>(rowcnt, csr, t, dinv, b2, out, N);
}